// Round 9
// baseline (3891.008 us; speedup 1.0000x reference)
//
#include <hip/hip_runtime.h>
#include <hip/hip_bf16.h>
#include <stdint.h>

typedef float  f32x4  __attribute__((ext_vector_type(4)));
typedef __bf16 bf16x8 __attribute__((ext_vector_type(8)));
typedef unsigned short u16x8 __attribute__((ext_vector_type(8)));

__device__ __forceinline__ unsigned short f2bf_rne(float f) {
    uint32_t x = __float_as_uint(f);
    uint32_t r = x + 0x7FFFu + ((x >> 16) & 1u);
    return (unsigned short)(r >> 16);
}

__global__ __launch_bounds__(256) void cvt_f32_bf16(const float* __restrict__ src,
                                                    unsigned short* __restrict__ dst,
                                                    long n) {
    long i0 = ((long)blockIdx.x * blockDim.x + threadIdx.x) * 8;
    long stride = (long)gridDim.x * blockDim.x * 8;
    for (long j = i0; j + 8 <= n; j += stride) {
        float4 v0 = *(const float4*)(src + j);
        float4 v1 = *(const float4*)(src + j + 4);
        u16x8 o;
        o[0] = f2bf_rne(v0.x); o[1] = f2bf_rne(v0.y);
        o[2] = f2bf_rne(v0.z); o[3] = f2bf_rne(v0.w);
        o[4] = f2bf_rne(v1.x); o[5] = f2bf_rne(v1.y);
        o[6] = f2bf_rne(v1.z); o[7] = f2bf_rne(v1.w);
        *(u16x8*)(dst + j) = o;
    }
}

#define GLL(SRC, DST) __builtin_amdgcn_global_load_lds(                      \
    (const __attribute__((address_space(1))) void*)(SRC),                    \
    (__attribute__((address_space(3))) void*)(DST), 16, 0, 0)
#define BARRIER() asm volatile("s_barrier" ::: "memory")
#define WAITV(N) asm volatile("s_waitcnt vmcnt(" #N ")" ::: "memory")
#define WAITL(N) do { asm volatile("s_waitcnt lgkmcnt(" #N ")" ::: "memory"); \
                      __builtin_amdgcn_sched_barrier(0); } while (0)

// Round-8 kernel (verified: 112 VGPR, 0 conflicts, super-tile swizzle) +
// lookahead-1 fragment prefetch with COUNTED lgkmcnt gates:
//   P1: issue bq1 [4]  -> gate lgkm(4)  (DS in-order: prior 12 drained)
//   P2: issue af1 [8]  -> gate lgkm(8)  (bq1 drained, af1 in flight)
//   P3: issue none     -> gate lgkm(0)  (af1 had a full phase to land)
//   P4: after vmcnt+barrier, issue next tile's af0+bq0 [12] -> hide under MFMA
// bq0 held P1->P4 (no re-read). bq set roles swap per tile parity.
// Register budget: 96 frag VGPR + 128 acc (AGPR) -- round-6-proven, no spill.
__global__ __launch_bounds__(512, 2) void gemm256_la(
    const unsigned short* __restrict__ A, const unsigned short* __restrict__ B,
    const float* __restrict__ bias, float* __restrict__ C,
    int M, int N, int K) {
    __shared__ __align__(16) char lds[131072];
    const int tid  = threadIdx.x;
    const int lane = tid & 63;
    const int wave = tid >> 6;
    const int wr  = wave >> 2;   // 0..1
    const int wc  = wave & 3;    // 0..3
    const int l15 = lane & 15;
    const int l4  = lane >> 4;

    // two-level XCD super-tile mapping (round-8 verified: FETCH -37%)
    const int nwg = gridDim.x;
    const int Nt  = N >> 8;
    const int Mt  = M >> 8;
    const int bid = blockIdx.x;
    int tm, tn;
    if ((Mt & 7) == 0 && (Nt & 3) == 0 && (nwg & 255) == 0) {
        const int nst = nwg >> 5;
        const int q2  = nst >> 3;
        const int xc  = bid & 7;
        const int oo  = bid >> 3;
        const int idx = oo & 31;
        const int h   = oo >> 5;
        const int st  = xc * q2 + h;
        const int Mst = Mt >> 3;
        const int stm = st % Mst;
        const int stn = st / Mst;
        tm = stm * 8 + (idx & 7);
        tn = stn * 4 + (idx >> 3);
    } else {
        int qq = nwg >> 3, rr = nwg & 7, xc = bid & 7, oo = bid >> 3;
        int wg = (xc < rr ? xc * (qq + 1) : rr * (qq + 1) + (xc - rr) * qq) + oo;
        tm = wg / Nt; tn = wg % Nt;
    }
    const long m0 = (long)tm << 8;
    const long n0 = (long)tn << 8;

    const int colSw = ((tid & 7) ^ ((tid >> 3) & 7)) << 3;
    const int aRow  = tid >> 3;
    const int bWcLo = tid >> 8;
    const int bR    = (tid >> 3) & 31;
    const long Kl = K;

    auto STAGE_A = [&](int buf, int u, int t) {
        char* dst = lds + (buf << 16) + (u << 14) + tid * 16;
        long col = (long)t * 64 + colSw;
#pragma unroll
        for (int i = 0; i < 2; ++i) {
            const unsigned short* src = A + (m0 + i * 128 + u * 64 + aRow) * Kl + col;
            GLL(src, dst + i * 8192);
        }
    };
    auto STAGE_B = [&](int buf, int u, int t) {
        char* dst = lds + (buf << 16) + 32768 + (u << 14) + tid * 16;
        long col = (long)t * 64 + colSw;
#pragma unroll
        for (int i = 0; i < 2; ++i) {
            const unsigned short* src = B + (n0 + (i * 2 + bWcLo) * 64 + u * 32 + bR) * Kl + col;
            GLL(src, dst + i * 8192);
        }
    };
    auto LDA = [&](int buf, int mh, int m, int kk) -> bf16x8 {
        int off = (((m * 16 + l15) * 64 + kk * 32 + l4 * 8) * 2) ^ ((l15 & 7) << 4);
        return *(const bf16x8*)(lds + (buf << 16) + (mh << 14) + (wr << 13) + off);
    };
    auto LDB = [&](int buf, int nh, int n, int kk) -> bf16x8 {
        int off = (((n * 16 + l15) * 64 + kk * 32 + l4 * 8) * 2) ^ ((l15 & 7) << 4);
        return *(const bf16x8*)(lds + (buf << 16) + 32768 + (nh << 14) + (wc << 12) + off);
    };

    f32x4 acc[8][4] = {};                    // 128 regs (AGPR-eligible)
    bf16x8 afE[4][2], afO[4][2];             // af0 / af1 of current tile
    bf16x8 bqX[2][2], bqY[2][2];             // bq roles swap per tile parity

    auto RD_A = [&](bf16x8 (&d)[4][2], int buf, int mh) {
#pragma unroll
        for (int m = 0; m < 4; ++m) { d[m][0] = LDA(buf, mh, m, 0); d[m][1] = LDA(buf, mh, m, 1); }
    };
    auto RD_B = [&](bf16x8 (&d)[2][2], int buf, int nh) {
#pragma unroll
        for (int n = 0; n < 2; ++n) { d[n][0] = LDB(buf, nh, n, 0); d[n][1] = LDB(buf, nh, n, 1); }
    };
    auto MFMA_Q = [&](bf16x8 (&af)[4][2], bf16x8 (&bq)[2][2], int mo, int no) {
        __builtin_amdgcn_s_setprio(1);
#pragma unroll
        for (int kk = 0; kk < 2; ++kk)
#pragma unroll
            for (int m = 0; m < 4; ++m)
#pragma unroll
                for (int n = 0; n < 2; ++n)
                    acc[mo + m][no + n] = __builtin_amdgcn_mfma_f32_16x16x32_bf16(
                        af[m][kk], bq[n][kk], acc[mo + m][no + n], 0, 0, 0);
        __builtin_amdgcn_s_setprio(0);
    };

    const int NT = K >> 6;

    // TILE(t, bq0s, bq1s): bq0s holds bq0(t) preloaded; bq1s receives bq1(t)
    // and, at P4, the NEXT tile's bq0.
    auto TILE = [&](int t, bf16x8 (&bq0s)[2][2], bf16x8 (&bq1s)[2][2]) {
        const int cur = t & 1, nxt = cur ^ 1;
        // P1: Q00 = afE x bq0 ; issue bq1 [4]; stage B(nxt,0,t+1)
        RD_B(bq1s, cur, 1);
        if (t + 1 < NT) STAGE_B(nxt, 0, t + 1);
        BARRIER(); WAITL(4);
        MFMA_Q(afE, bq0s, 0, 0);
        BARRIER();
        // P2: Q01 = afE x bq1 ; issue af1 [8]; stage A(cur,0,t+2)
        RD_A(afO, cur, 1);
        if (t + 2 < NT) STAGE_A(cur, 0, t + 2);
        BARRIER(); WAITL(8);
        MFMA_Q(afE, bq1s, 0, 2);
        BARRIER();
        // P3: Q11 = af1 x bq1 ; stage B(cur,1,t+2)
        if (t + 2 < NT) STAGE_B(cur, 1, t + 2);
        BARRIER(); WAITL(0);
        MFMA_Q(afO, bq1s, 4, 2);
        BARRIER();
        // P4: Q10 = af1 x bq0 ; stage A(cur,1,t+2); vmcnt gate; barrier;
        //     issue next tile's af0 [8] + bq0 [4] (into bq1s, free after P3)
        if (t + 2 < NT) STAGE_A(cur, 1, t + 2);
        if (t >= NT - 2) { WAITV(0); } else { WAITV(6); }
        BARRIER();
        if (t + 1 < NT) {
            RD_A(afE, nxt, 0);
            RD_B(bq1s, nxt, 0);
        }
        WAITL(12);   // no-op guard: afO/bq0s already drained; pins read-before-MFMA order
        MFMA_Q(afO, bq0s, 4, 0);
        BARRIER();
    };

    // prologue: tile0 (4 units) -> buf0; tile1 minus B0 -> buf1 (B0(1) staged in P1 of t=0)
    STAGE_A(0, 0, 0); STAGE_B(0, 0, 0); STAGE_B(0, 1, 0); STAGE_A(0, 1, 0);
    WAITV(4);
    STAGE_A(1, 0, 1); STAGE_B(1, 1, 1); STAGE_A(1, 1, 1);
    WAITV(6);
    BARRIER();
    RD_A(afE, 0, 0);     // af0 @ tile0
    RD_B(bqX, 0, 0);     // bq0 @ tile0

    for (int t = 0; t < NT; t += 2) {
        TILE(t,     bqX, bqY);
        TILE(t + 1, bqY, bqX);
    }

    // epilogue: D mapping col = l15, row = l4*4 + j within each 16x16 fragment
#pragma unroll
    for (int nf = 0; nf < 4; ++nf) {
        const long col = n0 + wc * 64 + nf * 16 + l15;
        const float bv = bias[col];
#pragma unroll
        for (int mf = 0; mf < 8; ++mf) {
            float* Cp = C + (m0 + wr * 128 + mf * 16 + l4 * 4) * (long)N + col;
#pragma unroll
            for (int j = 0; j < 4; ++j)
                Cp[(long)j * N] = acc[mf][nf][j] + bv;
        }
    }
}

// fallback: m97-structure 128x128 (verified round 1)
__global__ __launch_bounds__(256) void gemm_bt_bias(const unsigned short* __restrict__ A,
                                                    const unsigned short* __restrict__ B,
                                                    const float* __restrict__ bias,
                                                    float* __restrict__ C,
                                                    int M, int N, int K) {
    __shared__ unsigned short lds_a[128 * 32];
    __shared__ unsigned short lds_b[128 * 32];
    const int tid  = threadIdx.x;
    const int lane = tid & 63;
    const int wave = tid >> 6;
    const int wrr = wave >> 1, wcc = wave & 1;
    const int l15 = lane & 15, l4 = lane >> 4;
    const int nTilesN = N / 128;
    const long m0 = (long)(blockIdx.x / nTilesN) * 128;
    const long n0 = (long)(blockIdx.x % nTilesN) * 128;
    f32x4 acc[4][4] = {};
    const unsigned short* aSrc = A + (m0 + (tid >> 2)) * (long)K + ((tid & 3) * 8);
    const unsigned short* bSrc = B + (n0 + (tid >> 2)) * (long)K + ((tid & 3) * 8);
    char* aDst = (char*)lds_a + tid * 16;
    char* bDst = (char*)lds_b + tid * 16;
    for (int k0 = 0; k0 < K; k0 += 32) {
#pragma unroll
        for (int i = 0; i < 2; i++) {
            GLL(aSrc + (long)i * 64 * K + k0, aDst + i * 4096);
            GLL(bSrc + (long)i * 64 * K + k0, bDst + i * 4096);
        }
        __syncthreads();
        bf16x8 afr[4], bfr[4];
#pragma unroll
        for (int r = 0; r < 4; r++)
            afr[r] = *(const bf16x8*)&lds_a[(wrr * 64 + r * 16 + l15) * 32 + l4 * 8];
#pragma unroll
        for (int c = 0; c < 4; c++)
            bfr[c] = *(const bf16x8*)&lds_b[(wcc * 64 + c * 16 + l15) * 32 + l4 * 8];
#pragma unroll
        for (int r = 0; r < 4; r++)
#pragma unroll
            for (int c = 0; c < 4; c++)
                acc[r][c] = __builtin_amdgcn_mfma_f32_16x16x32_bf16(afr[r], bfr[c], acc[r][c], 0, 0, 0);
        __syncthreads();
    }
#pragma unroll
    for (int c = 0; c < 4; c++) {
        const long n = n0 + wcc * 64 + c * 16 + l15;
        const float bv = bias[n];
#pragma unroll
        for (int r = 0; r < 4; r++) {
            const long m = m0 + wrr * 64 + r * 16 + l4 * 4;
            float* Cp = C + m * (long)N + n;
#pragma unroll
            for (int j = 0; j < 4; j++)
                Cp[(long)j * N] = acc[r][c][j] + bv;
        }
    }
}

extern "C" void kernel_launch(void* const* d_in, const int* in_sizes, int n_in,
                              void* d_out, int out_size, void* d_ws, size_t ws_size,
                              hipStream_t stream) {
    const float* x    = (const float*)d_in[0];
    const float* w    = (const float*)d_in[1];
    const float* bias = (const float*)d_in[2];
    float* out = (float*)d_out;

    const long Nn = in_sizes[2];             // OUT = 4096
    const long Kk = (long)in_sizes[1] / Nn;  // IN  = 16384
    const long Mm = (long)in_sizes[0] / Kk;  // B*S = 8192

    unsigned short* aB = (unsigned short*)d_ws;
    unsigned short* bB = aB + Mm * Kk;
    cvt_f32_bf16<<<2048, 256, 0, stream>>>(x, aB, Mm * Kk);
    cvt_f32_bf16<<<2048, 256, 0, stream>>>(w, bB, Nn * Kk);

    if ((Mm & 255) == 0 && (Nn & 255) == 0 && (Kk & 127) == 0 && Kk >= 256) {
        const int grid = (int)((Mm >> 8) * (Nn >> 8));
        gemm256_la<<<grid, 512, 0, stream>>>(aB, bB, bias, out, (int)Mm, (int)Nn, (int)Kk);
    } else {
        const int grid = (int)((Mm / 128) * (Nn / 128));
        gemm_bt_bias<<<grid, 256, 0, stream>>>(aB, bB, bias, out, (int)Mm, (int)Nn, (int)Kk);
    }
}

// Round 10
// 3807.962 us; speedup vs baseline: 1.0218x; 1.0218x over previous
//
#include <hip/hip_runtime.h>
#include <hip/hip_bf16.h>
#include <stdint.h>

typedef float  f32x4  __attribute__((ext_vector_type(4)));
typedef __bf16 bf16x8 __attribute__((ext_vector_type(8)));
typedef unsigned short u16x8 __attribute__((ext_vector_type(8)));

__device__ __forceinline__ unsigned short f2bf_rne(float f) {
    uint32_t x = __float_as_uint(f);
    uint32_t r = x + 0x7FFFu + ((x >> 16) & 1u);
    return (unsigned short)(r >> 16);
}

__global__ __launch_bounds__(256) void cvt_f32_bf16(const float* __restrict__ src,
                                                    unsigned short* __restrict__ dst,
                                                    long n) {
    long i0 = ((long)blockIdx.x * blockDim.x + threadIdx.x) * 8;
    long stride = (long)gridDim.x * blockDim.x * 8;
    for (long j = i0; j + 8 <= n; j += stride) {
        float4 v0 = *(const float4*)(src + j);
        float4 v1 = *(const float4*)(src + j + 4);
        u16x8 o;
        o[0] = f2bf_rne(v0.x); o[1] = f2bf_rne(v0.y);
        o[2] = f2bf_rne(v0.z); o[3] = f2bf_rne(v0.w);
        o[4] = f2bf_rne(v1.x); o[5] = f2bf_rne(v1.y);
        o[6] = f2bf_rne(v1.z); o[7] = f2bf_rne(v1.w);
        *(u16x8*)(dst + j) = o;
    }
}

#define GLL(SRC, DST) __builtin_amdgcn_global_load_lds(                      \
    (const __attribute__((address_space(1))) void*)(SRC),                    \
    (__attribute__((address_space(3))) void*)(DST), 16, 0, 0)
#define BARRIER() asm volatile("s_barrier" ::: "memory")
#define WAITV(N) asm volatile("s_waitcnt vmcnt(" #N ")" ::: "memory")

// 256x256, BK=64, 8 waves. A staged in LDS (2x32KB dbuf, 0-conflict swizzled
// layout, round-2-verified). B read DIRECTLY global->VGPR (L2-hot via
// super-tile swizzle) -- removes 8/24 ds_reads per tile per wave (DS pipe
// 2304->1536 cyc/tile < MFMA 2483) and all B staging. Compiler auto-gates
// B-reg and ds-read readiness; manual vmcnt only for GLL->LDS visibility:
// WAITV(12)@P4 forces this pair's P1 A-stage (+older) landed;
// WAITV(6)@P8 forces P3g/P4g landed. Named register sets only (no
// parameter ping-pong -- rounds 3/9 spill lesson).
__global__ __launch_bounds__(512, 2) void gemm256_bg(
    const unsigned short* __restrict__ A, const unsigned short* __restrict__ B,
    const float* __restrict__ bias, float* __restrict__ C,
    int M, int N, int K) {
    __shared__ __align__(16) char lds[65536];
    const int tid  = threadIdx.x;
    const int lane = tid & 63;
    const int wave = tid >> 6;
    const int wr  = wave >> 2;   // 0..1
    const int wc  = wave & 3;    // 0..3
    const int l15 = lane & 15;
    const int l4  = lane >> 4;

    // two-level XCD super-tile mapping (round-8 verified: FETCH -37%)
    const int nwg = gridDim.x;
    const int Nt  = N >> 8;
    const int Mt  = M >> 8;
    const int bid = blockIdx.x;
    int tm, tn;
    if ((Mt & 7) == 0 && (Nt & 3) == 0 && (nwg & 255) == 0) {
        const int nst = nwg >> 5;
        const int q2  = nst >> 3;
        const int xc  = bid & 7;
        const int oo  = bid >> 3;
        const int idx = oo & 31;
        const int h   = oo >> 5;
        const int st  = xc * q2 + h;
        const int Mst = Mt >> 3;
        const int stm = st % Mst;
        const int stn = st / Mst;
        tm = stm * 8 + (idx & 7);
        tn = stn * 4 + (idx >> 3);
    } else {
        int qq = nwg >> 3, rr = nwg & 7, xc = bid & 7, oo = bid >> 3;
        int wg = (xc < rr ? xc * (qq + 1) : rr * (qq + 1) + (xc - rr) * qq) + oo;
        tm = wg / Nt; tn = wg % Nt;
    }
    const long m0 = (long)tm << 8;
    const long n0 = (long)tn << 8;

    const int colSw = ((tid & 7) ^ ((tid >> 3) & 7)) << 3;
    const int aRow  = tid >> 3;
    const long Kl = K;

    // A staging (identical geometry to round 2; buf stride now 32KB)
    auto STAGE_A = [&](int buf, int u, int t) {
        char* dst = lds + (buf << 15) + (u << 14) + tid * 16;
        long col = (long)t * 64 + colSw;
#pragma unroll
        for (int i = 0; i < 2; ++i) {
            const unsigned short* src = A + (m0 + i * 128 + u * 64 + aRow) * Kl + col;
            GLL(src, dst + i * 8192);
        }
    };
    auto LDA = [&](int buf, int mh, int m, int kk) -> bf16x8 {
        int off = (((m * 16 + l15) * 64 + kk * 32 + l4 * 8) * 2) ^ ((l15 & 7) << 4);
        return *(const bf16x8*)(lds + (buf << 15) + (mh << 14) + (wr << 13) + off);
    };
    // B fragment direct from global: row = n0 + wc*64 + nh*32 + n*16 + l15,
    // k = t*64 + kk*32 + l4*8 (16B aligned, L2-hot)
    const unsigned short* Bbase = B + (n0 + wc * 64 + l15) * Kl + l4 * 8;
    auto LDBG = [&](int nh, int n, int t, int kk) -> bf16x8 {
        return *(const bf16x8*)(Bbase + (nh * 32 + n * 16) * Kl + t * 64 + kk * 32);
    };

    f32x4 acc[8][4] = {};
    bf16x8 afA[4][2], afB[4][2], afA2[4][2], afB2[4][2];
    bf16x8 bqA[2][2], bqB[2][2], bqA2[2][2], bqB2[2][2];

    auto RD_A = [&](bf16x8 (&d)[4][2], int buf, int mh) {
#pragma unroll
        for (int m = 0; m < 4; ++m) { d[m][0] = LDA(buf, mh, m, 0); d[m][1] = LDA(buf, mh, m, 1); }
    };
    auto RD_BG = [&](bf16x8 (&d)[2][2], int nh, int t) {
#pragma unroll
        for (int n = 0; n < 2; ++n) { d[n][0] = LDBG(nh, n, t, 0); d[n][1] = LDBG(nh, n, t, 1); }
    };
    auto MFMA_Q = [&](bf16x8 (&af)[4][2], bf16x8 (&bq)[2][2], int mo, int no) {
        __builtin_amdgcn_s_setprio(1);
#pragma unroll
        for (int kk = 0; kk < 2; ++kk)
#pragma unroll
            for (int m = 0; m < 4; ++m)
#pragma unroll
                for (int n = 0; n < 2; ++n)
                    acc[mo + m][no + n] = __builtin_amdgcn_mfma_f32_16x16x32_bf16(
                        af[m][kk], bq[n][kk], acc[mo + m][no + n], 0, 0, 0);
        __builtin_amdgcn_s_setprio(0);
    };

    const int NT = K >> 6;

    // prologue: stage A tiles 0 (buf0) and 1 (buf1); full drain (cold start)
    STAGE_A(0, 0, 0); STAGE_A(0, 1, 0);
    STAGE_A(1, 0, 1); STAGE_A(1, 1, 1);
    WAITV(0);
    BARRIER();
    RD_A(afA, 0, 0);          // A0 @ tile0
    RD_BG(bqA, 0, 0);         // B n-half0 @ tile0 (compiler-gated)

    // main pairs: even tile -> buf0, odd tile -> buf1
    for (int t = 0; t + 3 < NT; t += 2) {
        // P1: Q00(e); issue bqB(e,nh1); stage A0(buf0, t+2)
        RD_BG(bqB, 1, t);
        STAGE_A(0, 0, t + 2);
        BARRIER();
        MFMA_Q(afA, bqA, 0, 0);
        BARRIER();
        // P2: Q01(e); prefetch afB(A1 buf0)
        RD_A(afB, 0, 1);
        BARRIER();
        MFMA_Q(afA, bqB, 0, 2);
        BARRIER();
        // P3: Q11(e); prefetch afA2(A0 buf1); stage A1(buf0, t+2)
        RD_A(afA2, 1, 0);
        STAGE_A(0, 1, t + 2);
        BARRIER();
        MFMA_Q(afB, bqB, 4, 2);
        BARRIER();
        // P4: Q10(e); issue bqA2,bqB2 (t+1); stage A0(buf1, t+3); GLL gate
        RD_BG(bqA2, 0, t + 1);
        RD_BG(bqB2, 1, t + 1);
        STAGE_A(1, 0, t + 3);
        WAITV(12);      // newest 12 = P4{8B+2G}+P3g2 -> forces P1g + older landed
        BARRIER();
        MFMA_Q(afB, bqA, 4, 0);
        BARRIER();
        // P5: Q00(o)
        BARRIER();
        MFMA_Q(afA2, bqA2, 0, 0);
        BARRIER();
        // P6: Q01(o); prefetch afB2(A1 buf1)
        RD_A(afB2, 1, 1);
        BARRIER();
        MFMA_Q(afA2, bqB2, 0, 2);
        BARRIER();
        // P7: Q11(o); prefetch afA(A0 buf0, t+2); stage A1(buf1, t+3)
        RD_A(afA, 0, 0);
        STAGE_A(1, 1, t + 3);
        BARRIER();
        MFMA_Q(afB2, bqB2, 4, 2);
        BARRIER();
        // P8: Q10(o); issue bqA(t+2, nh0); GLL gate
        RD_BG(bqA, 0, t + 2);
        WAITV(6);       // newest 6 = P8b4+P7g2 -> forces P3g,P4g landed
        BARRIER();
        MFMA_Q(afB2, bqA2, 4, 0);
        BARRIER();
    }

    // tail: tiles NT-2 (buf0), NT-1 (buf1); afA+bqA preloaded; all A staged
    {
        const int te = NT - 2, to = NT - 1;
        RD_BG(bqB, 1, te);
        WAITV(0);
        BARRIER();
        MFMA_Q(afA, bqA, 0, 0);
        BARRIER();
        RD_A(afB, 0, 1);
        BARRIER();
        MFMA_Q(afA, bqB, 0, 2);
        BARRIER();
        RD_A(afA2, 1, 0);
        BARRIER();
        MFMA_Q(afB, bqB, 4, 2);
        BARRIER();
        RD_BG(bqA2, 0, to);
        RD_BG(bqB2, 1, to);
        BARRIER();
        MFMA_Q(afB, bqA, 4, 0);
        BARRIER();
        MFMA_Q(afA2, bqA2, 0, 0);
        BARRIER();
        RD_A(afB2, 1, 1);
        BARRIER();
        MFMA_Q(afA2, bqB2, 0, 2);
        BARRIER();
        MFMA_Q(afB2, bqB2, 4, 2);
        MFMA_Q(afB2, bqA2, 4, 0);
    }

    // epilogue: D mapping col = l15, row = l4*4 + j within each 16x16 fragment
#pragma unroll
    for (int nf = 0; nf < 4; ++nf) {
        const long col = n0 + wc * 64 + nf * 16 + l15;
        const float bv = bias[col];
#pragma unroll
        for (int mf = 0; mf < 8; ++mf) {
            float* Cp = C + (m0 + wr * 128 + mf * 16 + l4 * 4) * (long)N + col;
#pragma unroll
            for (int j = 0; j < 4; ++j)
                Cp[(long)j * N] = acc[mf][nf][j] + bv;
        }
    }
}

// fallback: m97-structure 128x128 (verified round 1)
__global__ __launch_bounds__(256) void gemm_bt_bias(const unsigned short* __restrict__ A,
                                                    const unsigned short* __restrict__ B,
                                                    const float* __restrict__ bias,
                                                    float* __restrict__ C,
                                                    int M, int N, int K) {
    __shared__ unsigned short lds_a[128 * 32];
    __shared__ unsigned short lds_b[128 * 32];
    const int tid  = threadIdx.x;
    const int lane = tid & 63;
    const int wave = tid >> 6;
    const int wrr = wave >> 1, wcc = wave & 1;
    const int l15 = lane & 15, l4 = lane >> 4;
    const int nTilesN = N / 128;
    const long m0 = (long)(blockIdx.x / nTilesN) * 128;
    const long n0 = (long)(blockIdx.x % nTilesN) * 128;
    f32x4 acc[4][4] = {};
    const unsigned short* aSrc = A + (m0 + (tid >> 2)) * (long)K + ((tid & 3) * 8);
    const unsigned short* bSrc = B + (n0 + (tid >> 2)) * (long)K + ((tid & 3) * 8);
    char* aDst = (char*)lds_a + tid * 16;
    char* bDst = (char*)lds_b + tid * 16;
    for (int k0 = 0; k0 < K; k0 += 32) {
#pragma unroll
        for (int i = 0; i < 2; i++) {
            GLL(aSrc + (long)i * 64 * K + k0, aDst + i * 4096);
            GLL(bSrc + (long)i * 64 * K + k0, bDst + i * 4096);
        }
        __syncthreads();
        bf16x8 afr[4], bfr[4];
#pragma unroll
        for (int r = 0; r < 4; r++)
            afr[r] = *(const bf16x8*)&lds_a[(wrr * 64 + r * 16 + l15) * 32 + l4 * 8];
#pragma unroll
        for (int c = 0; c < 4; c++)
            bfr[c] = *(const bf16x8*)&lds_b[(wcc * 64 + c * 16 + l15) * 32 + l4 * 8];
#pragma unroll
        for (int r = 0; r < 4; r++)
#pragma unroll
            for (int c = 0; c < 4; c++)
                acc[r][c] = __builtin_amdgcn_mfma_f32_16x16x32_bf16(afr[r], bfr[c], acc[r][c], 0, 0, 0);
        __syncthreads();
    }
#pragma unroll
    for (int c = 0; c < 4; c++) {
        const long n = n0 + wcc * 64 + c * 16 + l15;
        const float bv = bias[n];
#pragma unroll
        for (int r = 0; r < 4; r++) {
            const long m = m0 + wrr * 64 + r * 16 + l4 * 4;
            float* Cp = C + m * (long)N + n;
#pragma unroll
            for (int j = 0; j < 4; j++)
                Cp[(long)j * N] = acc[r][c][j] + bv;
        }
    }
}

extern "C" void kernel_launch(void* const* d_in, const int* in_sizes, int n_in,
                              void* d_out, int out_size, void* d_ws, size_t ws_size,
                              hipStream_t stream) {
    const float* x    = (const float*)d_in[0];
    const float* w    = (const float*)d_in[1];
    const float* bias = (const float*)d_in[2];
    float* out = (float*)d_out;

    const long Nn = in_sizes[2];             // OUT = 4096
    const long Kk = (long)in_sizes[1] / Nn;  // IN  = 16384
    const long Mm = (long)in_sizes[0] / Kk;  // B*S = 8192

    unsigned short* aB = (unsigned short*)d_ws;
    unsigned short* bB = aB + Mm * Kk;
    cvt_f32_bf16<<<2048, 256, 0, stream>>>(x, aB, Mm * Kk);
    cvt_f32_bf16<<<2048, 256, 0, stream>>>(w, bB, Nn * Kk);

    if ((Mm & 255) == 0 && (Nn & 255) == 0 && (Kk & 127) == 0 && Kk >= 256) {
        const int grid = (int)((Mm >> 8) * (Nn >> 8));
        gemm256_bg<<<grid, 512, 0, stream>>>(aB, bB, bias, out, (int)Mm, (int)Nn, (int)Kk);
    } else {
        const int grid = (int)((Mm / 128) * (Nn / 128));
        gemm_bt_bias<<<grid, 256, 0, stream>>>(aB, bB, bias, out, (int)Mm, (int)Nn, (int)Kk);
    }
}

// Round 11
// 2070.966 us; speedup vs baseline: 1.8788x; 1.8387x over previous
//
#include <hip/hip_runtime.h>
#include <hip/hip_bf16.h>
#include <stdint.h>

typedef float  f32x4  __attribute__((ext_vector_type(4)));
typedef __bf16 bf16x8 __attribute__((ext_vector_type(8)));
typedef unsigned short u16x8 __attribute__((ext_vector_type(8)));

__device__ __forceinline__ unsigned short f2bf_rne(float f) {
    uint32_t x = __float_as_uint(f);
    uint32_t r = x + 0x7FFFu + ((x >> 16) & 1u);
    return (unsigned short)(r >> 16);
}

__global__ __launch_bounds__(256) void cvt_f32_bf16(const float* __restrict__ src,
                                                    unsigned short* __restrict__ dst,
                                                    long n) {
    long i0 = ((long)blockIdx.x * blockDim.x + threadIdx.x) * 8;
    long stride = (long)gridDim.x * blockDim.x * 8;
    for (long j = i0; j + 8 <= n; j += stride) {
        float4 v0 = *(const float4*)(src + j);
        float4 v1 = *(const float4*)(src + j + 4);
        u16x8 o;
        o[0] = f2bf_rne(v0.x); o[1] = f2bf_rne(v0.y);
        o[2] = f2bf_rne(v0.z); o[3] = f2bf_rne(v0.w);
        o[4] = f2bf_rne(v1.x); o[5] = f2bf_rne(v1.y);
        o[6] = f2bf_rne(v1.z); o[7] = f2bf_rne(v1.w);
        *(u16x8*)(dst + j) = o;
    }
}

#define GLL(SRC, DST) __builtin_amdgcn_global_load_lds(                      \
    (const __attribute__((address_space(1))) void*)(SRC),                    \
    (__attribute__((address_space(3))) void*)(DST), 16, 0, 0)
#define BARRIER() asm volatile("s_barrier" ::: "memory")
#define WAITV(N) asm volatile("s_waitcnt vmcnt(" #N ")" ::: "memory")
#define WAITL(N) do { asm volatile("s_waitcnt lgkmcnt(" #N ")" ::: "memory"); \
                      __builtin_amdgcn_sched_barrier(0); } while (0)

// 256x256, BK=64, 8 waves. A in LDS (2x32KB dbuf, 0-conflict layout).
// B direct global->VGPR (L2-hot via super-tile swizzle; addressing verified
// round 10). Software-pipelined 4-phase tile, NO phase exposes load latency:
//   P1: Q00(af,bq)        [af drained by WAITL(0): read a full tile-phase ago]
//   P2: read af2(mh1);        Q01(af,bq2)   [bq2 preloaded prev P4]
//   P3: read next-af(mh0) + stage u0(t+2); WAITL(8) drains af2; Q11(af2,bq2)
//   P4: stage u1(t+2); Q10(af2,bq); load bq,bq2(t+1) AFTER last use
// Frag regs: af32+af2_32+bq16+bq2_16 = 96 (round-6-proven, no spill).
// acc = 128 AGPR. All vmcnt gates compiler-managed (in-order vm counter
// drains older GLLs automatically each tile -> buf(t+1) visibility free).
__global__ __launch_bounds__(512, 2) void gemm256_bd(
    const unsigned short* __restrict__ A, const unsigned short* __restrict__ B,
    const float* __restrict__ bias, float* __restrict__ C,
    int M, int N, int K) {
    __shared__ __align__(16) char lds[65536];
    const int tid  = threadIdx.x;
    const int lane = tid & 63;
    const int wave = tid >> 6;
    const int wr  = wave >> 2;   // 0..1
    const int wc  = wave & 3;    // 0..3
    const int l15 = lane & 15;
    const int l4  = lane >> 4;

    // two-level XCD super-tile mapping (round-8 verified: FETCH -37%)
    const int nwg = gridDim.x;
    const int Nt  = N >> 8;
    const int Mt  = M >> 8;
    const int bid = blockIdx.x;
    int tm, tn;
    if ((Mt & 7) == 0 && (Nt & 3) == 0 && (nwg & 255) == 0) {
        const int nst = nwg >> 5;
        const int q2  = nst >> 3;
        const int xc  = bid & 7;
        const int oo  = bid >> 3;
        const int idx = oo & 31;
        const int h   = oo >> 5;
        const int st  = xc * q2 + h;
        const int Mst = Mt >> 3;
        const int stm = st % Mst;
        const int stn = st / Mst;
        tm = stm * 8 + (idx & 7);
        tn = stn * 4 + (idx >> 3);
    } else {
        int qq = nwg >> 3, rr = nwg & 7, xc = bid & 7, oo = bid >> 3;
        int wg = (xc < rr ? xc * (qq + 1) : rr * (qq + 1) + (xc - rr) * qq) + oo;
        tm = wg / Nt; tn = wg % Nt;
    }
    const long m0 = (long)tm << 8;
    const long n0 = (long)tn << 8;

    const int colSw = ((tid & 7) ^ ((tid >> 3) & 7)) << 3;
    const int aRow  = tid >> 3;
    const long Kl = K;

    auto STAGE_A = [&](int buf, int u, int t) {
        char* dst = lds + (buf << 15) + (u << 14) + tid * 16;
        long col = (long)t * 64 + colSw;
#pragma unroll
        for (int i = 0; i < 2; ++i) {
            const unsigned short* src = A + (m0 + i * 128 + u * 64 + aRow) * Kl + col;
            GLL(src, dst + i * 8192);
        }
    };
    auto LDA = [&](int buf, int mh, int m, int kk) -> bf16x8 {
        int off = (((m * 16 + l15) * 64 + kk * 32 + l4 * 8) * 2) ^ ((l15 & 7) << 4);
        return *(const bf16x8*)(lds + (buf << 15) + (mh << 14) + (wr << 13) + off);
    };
    const unsigned short* Bbase = B + (n0 + wc * 64 + l15) * Kl + l4 * 8;
    auto LDBG = [&](int nh, int n, int t, int kk) -> bf16x8 {
        return *(const bf16x8*)(Bbase + (nh * 32 + n * 16) * Kl + t * 64 + kk * 32);
    };

    f32x4 acc[8][4] = {};                 // 128 AGPR
    bf16x8 af[4][2], af2[4][2];           // 64 regs, fixed roles (mh0 / mh1)
    bf16x8 bq[2][2], bq2[2][2];           // 32 regs, fixed roles (nh0 / nh1)

    auto RD_A = [&](bf16x8 (&d)[4][2], int buf, int mh) {
#pragma unroll
        for (int m = 0; m < 4; ++m) { d[m][0] = LDA(buf, mh, m, 0); d[m][1] = LDA(buf, mh, m, 1); }
    };
    auto RD_BG = [&](bf16x8 (&d)[2][2], int nh, int t) {
#pragma unroll
        for (int n = 0; n < 2; ++n) { d[n][0] = LDBG(nh, n, t, 0); d[n][1] = LDBG(nh, n, t, 1); }
    };
    auto MFMA_Q = [&](bf16x8 (&a_)[4][2], bf16x8 (&b_)[2][2], int mo, int no) {
        __builtin_amdgcn_s_setprio(1);
#pragma unroll
        for (int kk = 0; kk < 2; ++kk)
#pragma unroll
            for (int m = 0; m < 4; ++m)
#pragma unroll
                for (int n = 0; n < 2; ++n)
                    acc[mo + m][no + n] = __builtin_amdgcn_mfma_f32_16x16x32_bf16(
                        a_[m][kk], b_[n][kk], acc[mo + m][no + n], 0, 0, 0);
        __builtin_amdgcn_s_setprio(0);
    };

    const int NT = K >> 6;

    // prologue: stage A tiles 0 (buf0), 1 (buf1); drain; preload tile0 operands
    STAGE_A(0, 0, 0); STAGE_A(0, 1, 0);
    STAGE_A(1, 0, 1); STAGE_A(1, 1, 1);
    WAITV(0);
    BARRIER();
    RD_A(af, 0, 0);                 // tile0 mh0 (drained at t=0 P1)
    RD_BG(bq, 0, 0);                // tile0 nh0
    RD_BG(bq2, 1, 0);               // tile0 nh1

    for (int t = 0; t < NT; ++t) {
        const int c = t & 1, nxt = c ^ 1;
        // ---- P1: Q00 ----
        WAITL(0);                   // af(mh0, t) ready (read 2 phases ago)
        MFMA_Q(af, bq, 0, 0);       // compiler vmcnt gate for bq (preloaded prev P4)
        BARRIER();
        // ---- P2: read af2; Q01 ----
        RD_A(af2, c, 1);            // 8 ds, drained at P3
        MFMA_Q(af, bq2, 0, 2);
        BARRIER();
        // ---- P3: read next af; stage u0(t+2); Q11 ----
        if (t + 2 < NT) STAGE_A(c, 0, t + 2);
        if (t + 1 < NT) {
            RD_A(af, nxt, 0);       // next tile mh0 (buf published at P1-end barrier)
            WAITL(8);               // drain af2, keep next-af 8 in flight
        } else {
            WAITL(0);
        }
        MFMA_Q(af2, bq2, 4, 2);
        BARRIER();
        // ---- P4: stage u1(t+2); Q10; preload next bq/bq2 after last use ----
        if (t + 2 < NT) STAGE_A(c, 1, t + 2);
        MFMA_Q(af2, bq, 4, 0);
        if (t + 1 < NT) {
            RD_BG(bq,  0, t + 1);
            RD_BG(bq2, 1, t + 1);
        }
        BARRIER();
    }

    // epilogue: D mapping col = l15, row = l4*4 + j within each 16x16 fragment
#pragma unroll
    for (int nf = 0; nf < 4; ++nf) {
        const long col = n0 + wc * 64 + nf * 16 + l15;
        const float bv = bias[col];
#pragma unroll
        for (int mf = 0; mf < 8; ++mf) {
            float* Cp = C + (m0 + wr * 128 + mf * 16 + l4 * 4) * (long)N + col;
#pragma unroll
            for (int j = 0; j < 4; ++j)
                Cp[(long)j * N] = acc[mf][nf][j] + bv;
        }
    }
}

// fallback: m97-structure 128x128 (verified round 1)
__global__ __launch_bounds__(256) void gemm_bt_bias(const unsigned short* __restrict__ A,
                                                    const unsigned short* __restrict__ B,
                                                    const float* __restrict__ bias,
                                                    float* __restrict__ C,
                                                    int M, int N, int K) {
    __shared__ unsigned short lds_a[128 * 32];
    __shared__ unsigned short lds_b[128 * 32];
    const int tid  = threadIdx.x;
    const int lane = tid & 63;
    const int wave = tid >> 6;
    const int wrr = wave >> 1, wcc = wave & 1;
    const int l15 = lane & 15, l4 = lane >> 4;
    const int nTilesN = N / 128;
    const long m0 = (long)(blockIdx.x / nTilesN) * 128;
    const long n0 = (long)(blockIdx.x % nTilesN) * 128;
    f32x4 acc[4][4] = {};
    const unsigned short* aSrc = A + (m0 + (tid >> 2)) * (long)K + ((tid & 3) * 8);
    const unsigned short* bSrc = B + (n0 + (tid >> 2)) * (long)K + ((tid & 3) * 8);
    char* aDst = (char*)lds_a + tid * 16;
    char* bDst = (char*)lds_b + tid * 16;
    for (int k0 = 0; k0 < K; k0 += 32) {
#pragma unroll
        for (int i = 0; i < 2; i++) {
            GLL(aSrc + (long)i * 64 * K + k0, aDst + i * 4096);
            GLL(bSrc + (long)i * 64 * K + k0, bDst + i * 4096);
        }
        __syncthreads();
        bf16x8 afr[4], bfr[4];
#pragma unroll
        for (int r = 0; r < 4; r++)
            afr[r] = *(const bf16x8*)&lds_a[(wrr * 64 + r * 16 + l15) * 32 + l4 * 8];
#pragma unroll
        for (int c = 0; c < 4; c++)
            bfr[c] = *(const bf16x8*)&lds_b[(wcc * 64 + c * 16 + l15) * 32 + l4 * 8];
#pragma unroll
        for (int r = 0; r < 4; r++)
#pragma unroll
            for (int c = 0; c < 4; c++)
                acc[r][c] = __builtin_amdgcn_mfma_f32_16x16x32_bf16(afr[r], bfr[c], acc[r][c], 0, 0, 0);
        __syncthreads();
    }
#pragma unroll
    for (int c = 0; c < 4; c++) {
        const long n = n0 + wcc * 64 + c * 16 + l15;
        const float bv = bias[n];
#pragma unroll
        for (int r = 0; r < 4; r++) {
            const long m = m0 + wrr * 64 + r * 16 + l4 * 4;
            float* Cp = C + m * (long)N + n;
#pragma unroll
            for (int j = 0; j < 4; j++)
                Cp[(long)j * N] = acc[r][c][j] + bv;
        }
    }
}

extern "C" void kernel_launch(void* const* d_in, const int* in_sizes, int n_in,
                              void* d_out, int out_size, void* d_ws, size_t ws_size,
                              hipStream_t stream) {
    const float* x    = (const float*)d_in[0];
    const float* w    = (const float*)d_in[1];
    const float* bias = (const float*)d_in[2];
    float* out = (float*)d_out;

    const long Nn = in_sizes[2];             // OUT = 4096
    const long Kk = (long)in_sizes[1] / Nn;  // IN  = 16384
    const long Mm = (long)in_sizes[0] / Kk;  // B*S = 8192

    unsigned short* aB = (unsigned short*)d_ws;
    unsigned short* bB = aB + Mm * Kk;
    cvt_f32_bf16<<<2048, 256, 0, stream>>>(x, aB, Mm * Kk);
    cvt_f32_bf16<<<2048, 256, 0, stream>>>(w, bB, Nn * Kk);

    if ((Mm & 255) == 0 && (Nn & 255) == 0 && (Kk & 127) == 0 && Kk >= 256) {
        const int grid = (int)((Mm >> 8) * (Nn >> 8));
        gemm256_bd<<<grid, 512, 0, stream>>>(aB, bB, bias, out, (int)Mm, (int)Nn, (int)Kk);
    } else {
        const int grid = (int)((Mm / 128) * (Nn / 128));
        gemm_bt_bias<<<grid, 256, 0, stream>>>(aB, bB, bias, out, (int)Mm, (int)Nn, (int)Kk);
    }
}

// Round 12
// 2055.762 us; speedup vs baseline: 1.8927x; 1.0074x over previous
//
#include <hip/hip_runtime.h>
#include <hip/hip_bf16.h>
#include <stdint.h>

typedef float  f32x4  __attribute__((ext_vector_type(4)));
typedef __bf16 bf16x8 __attribute__((ext_vector_type(8)));
typedef unsigned short u16x8 __attribute__((ext_vector_type(8)));

__device__ __forceinline__ unsigned short f2bf_rne(float f) {
    uint32_t x = __float_as_uint(f);
    uint32_t r = x + 0x7FFFu + ((x >> 16) & 1u);
    return (unsigned short)(r >> 16);
}

__global__ __launch_bounds__(256) void cvt_f32_bf16(const float* __restrict__ src,
                                                    unsigned short* __restrict__ dst,
                                                    long n) {
    long i0 = ((long)blockIdx.x * blockDim.x + threadIdx.x) * 8;
    long stride = (long)gridDim.x * blockDim.x * 8;
    for (long j = i0; j + 8 <= n; j += stride) {
        float4 v0 = *(const float4*)(src + j);
        float4 v1 = *(const float4*)(src + j + 4);
        u16x8 o;
        o[0] = f2bf_rne(v0.x); o[1] = f2bf_rne(v0.y);
        o[2] = f2bf_rne(v0.z); o[3] = f2bf_rne(v0.w);
        o[4] = f2bf_rne(v1.x); o[5] = f2bf_rne(v1.y);
        o[6] = f2bf_rne(v1.z); o[7] = f2bf_rne(v1.w);
        *(u16x8*)(dst + j) = o;
    }
}

#define GLL(SRC, DST) __builtin_amdgcn_global_load_lds(                      \
    (const __attribute__((address_space(1))) void*)(SRC),                    \
    (__attribute__((address_space(3))) void*)(DST), 16, 0, 0)
#define BARRIER() asm volatile("s_barrier" ::: "memory")
#define WAITV(N) asm volatile("s_waitcnt vmcnt(" #N ")" ::: "memory")
#define WAITL(N) do { asm volatile("s_waitcnt lgkmcnt(" #N ")" ::: "memory"); \
                      __builtin_amdgcn_sched_barrier(0); } while (0)

// 256x256, BK=64, 8 waves. A in LDS (2x32KB dbuf, 0-conflict layout).
// B direct global->VGPR (L2-hot; addressing verified r10/r11).
// KEY FIX vs r11: VM ISSUE ORDER. Loads to keep in flight are issued AFTER
// loads to be waited on; every gate is a counted vmcnt.
// Per tile t (c=t&1): P1 Q00(af,bq) | P2 Q10(af2,bq), issue bq(t+1)+u0g(t+2)
// | P3 Q01(af,bq2), issue af(t+1) ds | P4 Q11(af2,bq2), issue af2(t+1) ds +
// bq2(t+1)+u1g(t+2).  Steady-state outstanding @P1 = 12.
// WAITV(8)@P1 drains bq(t); WAITV(8)@P3 drains u0g(t+1)+bq2(t);
// WAITV(6)@P4 drains u1g(t+1). 3 barriers/tile. 96 frag regs (r6-proven).
// Peeled conservative 2-tile tail (guarded staging breaks the ledger).
__global__ __launch_bounds__(512, 2) void gemm256_v2(
    const unsigned short* __restrict__ A, const unsigned short* __restrict__ B,
    const float* __restrict__ bias, float* __restrict__ C,
    int M, int N, int K) {
    __shared__ __align__(16) char lds[65536];
    const int tid  = threadIdx.x;
    const int lane = tid & 63;
    const int wave = tid >> 6;
    const int wr  = wave >> 2;   // 0..1
    const int wc  = wave & 3;    // 0..3
    const int l15 = lane & 15;
    const int l4  = lane >> 4;

    // two-level XCD super-tile mapping (round-8 verified)
    const int nwg = gridDim.x;
    const int Nt  = N >> 8;
    const int Mt  = M >> 8;
    const int bid = blockIdx.x;
    int tm, tn;
    if ((Mt & 7) == 0 && (Nt & 3) == 0 && (nwg & 255) == 0) {
        const int nst = nwg >> 5;
        const int q2  = nst >> 3;
        const int xc  = bid & 7;
        const int oo  = bid >> 3;
        const int idx = oo & 31;
        const int h   = oo >> 5;
        const int st  = xc * q2 + h;
        const int Mst = Mt >> 3;
        const int stm = st % Mst;
        const int stn = st / Mst;
        tm = stm * 8 + (idx & 7);
        tn = stn * 4 + (idx >> 3);
    } else {
        int qq = nwg >> 3, rr = nwg & 7, xc = bid & 7, oo = bid >> 3;
        int wg = (xc < rr ? xc * (qq + 1) : rr * (qq + 1) + (xc - rr) * qq) + oo;
        tm = wg / Nt; tn = wg % Nt;
    }
    const long m0 = (long)tm << 8;
    const long n0 = (long)tn << 8;

    const int colSw = ((tid & 7) ^ ((tid >> 3) & 7)) << 3;
    const int aRow  = tid >> 3;
    const long Kl = K;

    auto STAGE_A = [&](int buf, int u, int t) {
        char* dst = lds + (buf << 15) + (u << 14) + tid * 16;
        long col = (long)t * 64 + colSw;
#pragma unroll
        for (int i = 0; i < 2; ++i) {
            const unsigned short* src = A + (m0 + i * 128 + u * 64 + aRow) * Kl + col;
            GLL(src, dst + i * 8192);
        }
    };
    auto LDA = [&](int buf, int mh, int m, int kk) -> bf16x8 {
        int off = (((m * 16 + l15) * 64 + kk * 32 + l4 * 8) * 2) ^ ((l15 & 7) << 4);
        return *(const bf16x8*)(lds + (buf << 15) + (mh << 14) + (wr << 13) + off);
    };
    const unsigned short* Bbase = B + (n0 + wc * 64 + l15) * Kl + l4 * 8;
    auto LDBG = [&](int nh, int n, int t, int kk) -> bf16x8 {
        return *(const bf16x8*)(Bbase + (nh * 32 + n * 16) * Kl + t * 64 + kk * 32);
    };

    f32x4 acc[8][4] = {};                 // 128 AGPR
    bf16x8 af[4][2], af2[4][2];           // 64 regs, fixed roles (mh0/mh1)
    bf16x8 bq[2][2], bq2[2][2];           // 32 regs, fixed roles (nh0/nh1)

    auto RD_A = [&](bf16x8 (&d)[4][2], int buf, int mh) {
#pragma unroll
        for (int m = 0; m < 4; ++m) { d[m][0] = LDA(buf, mh, m, 0); d[m][1] = LDA(buf, mh, m, 1); }
    };
    auto RD_BG = [&](bf16x8 (&d)[2][2], int nh, int t) {
#pragma unroll
        for (int n = 0; n < 2; ++n) { d[n][0] = LDBG(nh, n, t, 0); d[n][1] = LDBG(nh, n, t, 1); }
    };
    auto MFMA_Q = [&](bf16x8 (&a_)[4][2], bf16x8 (&b_)[2][2], int mo, int no) {
        __builtin_amdgcn_s_setprio(1);
#pragma unroll
        for (int kk = 0; kk < 2; ++kk)
#pragma unroll
            for (int m = 0; m < 4; ++m)
#pragma unroll
                for (int n = 0; n < 2; ++n)
                    acc[mo + m][no + n] = __builtin_amdgcn_mfma_f32_16x16x32_bf16(
                        a_[m][kk], b_[n][kk], acc[mo + m][no + n], 0, 0, 0);
        __builtin_amdgcn_s_setprio(0);
    };

    const int NT = K >> 6;

    // prologue: stage tiles 0,1; drain; preload tile0 operands
    STAGE_A(0, 0, 0); STAGE_A(0, 1, 0);
    STAGE_A(1, 0, 1); STAGE_A(1, 1, 1);
    WAITV(0);
    BARRIER();
    RD_A(af, 0, 0);             // tile0 mh0
    RD_A(af2, 0, 1);            // tile0 mh1
    RD_BG(bq, 0, 0);            // tile0 nh0 (compiler-gated regs)
    RD_BG(bq2, 1, 0);           // tile0 nh1

    for (int t = 0; t < NT - 2; ++t) {
        const int c = t & 1, nxt = c ^ 1;
        // ---- P1: Q00 ----
        WAITV(8);               // drains bq(t) [oldest 4 of 12]
        WAITL(0);               // af/af2(t) ds ready
        MFMA_Q(af, bq, 0, 0);
        BARRIER();              // B1: u0(t)/u1(t) reads published -> re-stage safe
        // ---- P2: Q10 ; issue bq(t+1), u0g(t+2) ----
        MFMA_Q(af2, bq, 4, 0);
        RD_BG(bq, 0, t + 1);    // after bq's last use
        STAGE_A(c, 0, t + 2);
        // ---- P3: Q01 ; read af(t+1) ----
        WAITV(8);               // drains u0g(t+1) + bq2(t)
        BARRIER();              // B2: u0(t+1) visible to all waves
        MFMA_Q(af, bq2, 0, 2);
        RD_A(af, nxt, 0);       // after af's last use
        // ---- P4: Q11 ; read af2(t+1) ; issue bq2(t+1), u1g(t+2) ----
        WAITV(6);               // drains u1g(t+1)
        BARRIER();              // B3: u1(t+1) visible to all waves
        MFMA_Q(af2, bq2, 4, 2);
        RD_A(af2, nxt, 1);      // after af2's last use
        RD_BG(bq2, 1, t + 1);
        STAGE_A(c, 1, t + 2);
    }

    // tail: tiles NT-2, NT-1 (all staged; conservative gates)
    {
        const int c2 = (NT - 1) & 1;
        WAITV(0); WAITL(0);
        BARRIER();
        MFMA_Q(af, bq, 0, 0);
        MFMA_Q(af2, bq, 4, 0);
        RD_BG(bq, 0, NT - 1);
        MFMA_Q(af, bq2, 0, 2);
        RD_A(af, c2, 0);
        MFMA_Q(af2, bq2, 4, 2);
        RD_A(af2, c2, 1);
        RD_BG(bq2, 1, NT - 1);
        // last tile (compiler gates bq/bq2 regs; WAITL for af/af2)
        WAITL(0);
        MFMA_Q(af, bq, 0, 0);
        MFMA_Q(af2, bq, 4, 0);
        MFMA_Q(af, bq2, 0, 2);
        MFMA_Q(af2, bq2, 4, 2);
    }

    // epilogue: D mapping col = l15, row = l4*4 + j within each 16x16 fragment
#pragma unroll
    for (int nf = 0; nf < 4; ++nf) {
        const long col = n0 + wc * 64 + nf * 16 + l15;
        const float bv = bias[col];
#pragma unroll
        for (int mf = 0; mf < 8; ++mf) {
            float* Cp = C + (m0 + wr * 128 + mf * 16 + l4 * 4) * (long)N + col;
#pragma unroll
            for (int j = 0; j < 4; ++j)
                Cp[(long)j * N] = acc[mf][nf][j] + bv;
        }
    }
}

// fallback: m97-structure 128x128 (verified round 1)
__global__ __launch_bounds__(256) void gemm_bt_bias(const unsigned short* __restrict__ A,
                                                    const unsigned short* __restrict__ B,
                                                    const float* __restrict__ bias,
                                                    float* __restrict__ C,
                                                    int M, int N, int K) {
    __shared__ unsigned short lds_a[128 * 32];
    __shared__ unsigned short lds_b[128 * 32];
    const int tid  = threadIdx.x;
    const int lane = tid & 63;
    const int wave = tid >> 6;
    const int wrr = wave >> 1, wcc = wave & 1;
    const int l15 = lane & 15, l4 = lane >> 4;
    const int nTilesN = N / 128;
    const long m0 = (long)(blockIdx.x / nTilesN) * 128;
    const long n0 = (long)(blockIdx.x % nTilesN) * 128;
    f32x4 acc[4][4] = {};
    const unsigned short* aSrc = A + (m0 + (tid >> 2)) * (long)K + ((tid & 3) * 8);
    const unsigned short* bSrc = B + (n0 + (tid >> 2)) * (long)K + ((tid & 3) * 8);
    char* aDst = (char*)lds_a + tid * 16;
    char* bDst = (char*)lds_b + tid * 16;
    for (int k0 = 0; k0 < K; k0 += 32) {
#pragma unroll
        for (int i = 0; i < 2; i++) {
            GLL(aSrc + (long)i * 64 * K + k0, aDst + i * 4096);
            GLL(bSrc + (long)i * 64 * K + k0, bDst + i * 4096);
        }
        __syncthreads();
        bf16x8 afr[4], bfr[4];
#pragma unroll
        for (int r = 0; r < 4; r++)
            afr[r] = *(const bf16x8*)&lds_a[(wrr * 64 + r * 16 + l15) * 32 + l4 * 8];
#pragma unroll
        for (int c = 0; c < 4; c++)
            bfr[c] = *(const bf16x8*)&lds_b[(wcc * 64 + c * 16 + l15) * 32 + l4 * 8];
#pragma unroll
        for (int r = 0; r < 4; r++)
#pragma unroll
            for (int c = 0; c < 4; c++)
                acc[r][c] = __builtin_amdgcn_mfma_f32_16x16x32_bf16(afr[r], bfr[c], acc[r][c], 0, 0, 0);
        __syncthreads();
    }
#pragma unroll
    for (int c = 0; c < 4; c++) {
        const long n = n0 + wcc * 64 + c * 16 + l15;
        const float bv = bias[n];
#pragma unroll
        for (int r = 0; r < 4; r++) {
            const long m = m0 + wrr * 64 + r * 16 + l4 * 4;
            float* Cp = C + m * (long)N + n;
#pragma unroll
            for (int j = 0; j < 4; j++)
                Cp[(long)j * N] = acc[r][c][j] + bv;
        }
    }
}

extern "C" void kernel_launch(void* const* d_in, const int* in_sizes, int n_in,
                              void* d_out, int out_size, void* d_ws, size_t ws_size,
                              hipStream_t stream) {
    const float* x    = (const float*)d_in[0];
    const float* w    = (const float*)d_in[1];
    const float* bias = (const float*)d_in[2];
    float* out = (float*)d_out;

    const long Nn = in_sizes[2];             // OUT = 4096
    const long Kk = (long)in_sizes[1] / Nn;  // IN  = 16384
    const long Mm = (long)in_sizes[0] / Kk;  // B*S = 8192

    unsigned short* aB = (unsigned short*)d_ws;
    unsigned short* bB = aB + Mm * Kk;
    cvt_f32_bf16<<<2048, 256, 0, stream>>>(x, aB, Mm * Kk);
    cvt_f32_bf16<<<2048, 256, 0, stream>>>(w, bB, Nn * Kk);

    if ((Mm & 255) == 0 && (Nn & 255) == 0 && (Kk & 127) == 0 && Kk >= 256) {
        const int grid = (int)((Mm >> 8) * (Nn >> 8));
        gemm256_v2<<<grid, 512, 0, stream>>>(aB, bB, bias, out, (int)Mm, (int)Nn, (int)Kk);
    } else {
        const int grid = (int)((Mm / 128) * (Nn / 128));
        gemm_bt_bias<<<grid, 256, 0, stream>>>(aB, bB, bias, out, (int)Mm, (int)Nn, (int)Kk);
    }
}

// Round 13
// 1609.277 us; speedup vs baseline: 2.4179x; 1.2774x over previous
//
#include <hip/hip_runtime.h>
#include <hip/hip_bf16.h>
#include <stdint.h>

typedef float  f32x4  __attribute__((ext_vector_type(4)));
typedef __bf16 bf16x8 __attribute__((ext_vector_type(8)));
typedef unsigned short u16x8 __attribute__((ext_vector_type(8)));

__device__ __forceinline__ unsigned short f2bf_rne(float f) {
    uint32_t x = __float_as_uint(f);
    uint32_t r = x + 0x7FFFu + ((x >> 16) & 1u);
    return (unsigned short)(r >> 16);
}

__global__ __launch_bounds__(256) void cvt_f32_bf16(const float* __restrict__ src,
                                                    unsigned short* __restrict__ dst,
                                                    long n) {
    long i0 = ((long)blockIdx.x * blockDim.x + threadIdx.x) * 8;
    long stride = (long)gridDim.x * blockDim.x * 8;
    for (long j = i0; j + 8 <= n; j += stride) {
        float4 v0 = *(const float4*)(src + j);
        float4 v1 = *(const float4*)(src + j + 4);
        u16x8 o;
        o[0] = f2bf_rne(v0.x); o[1] = f2bf_rne(v0.y);
        o[2] = f2bf_rne(v0.z); o[3] = f2bf_rne(v0.w);
        o[4] = f2bf_rne(v1.x); o[5] = f2bf_rne(v1.y);
        o[6] = f2bf_rne(v1.z); o[7] = f2bf_rne(v1.w);
        *(u16x8*)(dst + j) = o;
    }
}

#define GLL(SRC, DST) __builtin_amdgcn_global_load_lds(                      \
    (const __attribute__((address_space(1))) void*)(SRC),                    \
    (__attribute__((address_space(3))) void*)(DST), 16, 0, 0)
#define BARRIER() asm volatile("s_barrier" ::: "memory")
#define WAITV(N) asm volatile("s_waitcnt vmcnt(" #N ")" ::: "memory")

// 256x256, BK=64, 8 waves, 128KB dbuf LDS, r8's 0-conflict layout/geometry.
// READ-AHEAD pipeline, NO manual lgkm gates (compiler emits exact counted
// lgkmcnt from register deps -- plain C++ ds_reads):
//   P4(t-1): [vmcnt gate+barrier] read af(t,u0)+bq(t,nh0);  Q11(t-1)
//   P1(t): stage Bnh0(t+1); read af2(t,u1);                 Q00(af,bq)   |bar
//   P2(t): stage Au0(t+2);  read bq2(t,nh1);                Q10(af2,bq)  |bar
//   P3(t): stage Au1(t+2);                                  Q01(af,bq2)  |bar
//   P4(t): stage Bnh1(t+2); vmcnt(6); bar; read t+1;        Q11(af2,bq2)
// Every read gets >= 1 full phase of MFMA latency cover. 4 barriers/tile.
// Fixed-role sets af/af2/bq/bq2 = 96 frag regs (r6-proven, no spill).
// Ledger: steady outstanding@P4 = 14; vmcnt(6) drains exactly tile t+1's
// 8 GLLs {Au0@P2(t-1), Au1@P3(t-1), Bnh1@P4(t-1), Bnh0@P1(t)}.
// vmcnt(0) for t>=NT-3 (guarded stages break the count; full drain is cheap).
__global__ __launch_bounds__(512, 2) void gemm256_pf(
    const unsigned short* __restrict__ A, const unsigned short* __restrict__ B,
    const float* __restrict__ bias, float* __restrict__ C,
    int M, int N, int K) {
    __shared__ __align__(16) char lds[131072];
    const int tid  = threadIdx.x;
    const int lane = tid & 63;
    const int wave = tid >> 6;
    const int wr  = wave >> 2;   // 0..1
    const int wc  = wave & 3;    // 0..3
    const int l15 = lane & 15;
    const int l4  = lane >> 4;

    // two-level XCD super-tile mapping (round-8 verified: FETCH -37%)
    const int nwg = gridDim.x;
    const int Nt  = N >> 8;
    const int Mt  = M >> 8;
    const int bid = blockIdx.x;
    int tm, tn;
    if ((Mt & 7) == 0 && (Nt & 3) == 0 && (nwg & 255) == 0) {
        const int nst = nwg >> 5;
        const int q2  = nst >> 3;
        const int xc  = bid & 7;
        const int oo  = bid >> 3;
        const int idx = oo & 31;
        const int h   = oo >> 5;
        const int st  = xc * q2 + h;
        const int Mst = Mt >> 3;
        const int stm = st % Mst;
        const int stn = st / Mst;
        tm = stm * 8 + (idx & 7);
        tn = stn * 4 + (idx >> 3);
    } else {
        int qq = nwg >> 3, rr = nwg & 7, xc = bid & 7, oo = bid >> 3;
        int wg = (xc < rr ? xc * (qq + 1) : rr * (qq + 1) + (xc - rr) * qq) + oo;
        tm = wg / Nt; tn = wg % Nt;
    }
    const long m0 = (long)tm << 8;
    const long n0 = (long)tn << 8;

    const int colSw = ((tid & 7) ^ ((tid >> 3) & 7)) << 3;
    const int aRow  = tid >> 3;
    const int bWcLo = tid >> 8;
    const int bR    = (tid >> 3) & 31;
    const long Kl = K;

    auto STAGE_A = [&](int buf, int u, int t) {
        char* dst = lds + (buf << 16) + (u << 14) + tid * 16;
        long col = (long)t * 64 + colSw;
#pragma unroll
        for (int i = 0; i < 2; ++i) {
            const unsigned short* src = A + (m0 + i * 128 + u * 64 + aRow) * Kl + col;
            GLL(src, dst + i * 8192);
        }
    };
    auto STAGE_B = [&](int buf, int u, int t) {
        char* dst = lds + (buf << 16) + 32768 + (u << 14) + tid * 16;
        long col = (long)t * 64 + colSw;
#pragma unroll
        for (int i = 0; i < 2; ++i) {
            const unsigned short* src = B + (n0 + (i * 2 + bWcLo) * 64 + u * 32 + bR) * Kl + col;
            GLL(src, dst + i * 8192);
        }
    };
    auto LDA = [&](int buf, int mh, int m, int kk) -> bf16x8 {
        int off = (((m * 16 + l15) * 64 + kk * 32 + l4 * 8) * 2) ^ ((l15 & 7) << 4);
        return *(const bf16x8*)(lds + (buf << 16) + (mh << 14) + (wr << 13) + off);
    };
    auto LDB = [&](int buf, int nh, int n, int kk) -> bf16x8 {
        int off = (((n * 16 + l15) * 64 + kk * 32 + l4 * 8) * 2) ^ ((l15 & 7) << 4);
        return *(const bf16x8*)(lds + (buf << 16) + 32768 + (nh << 14) + (wc << 12) + off);
    };

    f32x4 acc[8][4] = {};                 // 128 AGPR
    bf16x8 af[4][2], af2[4][2];           // fixed roles: mh0 / mh1
    bf16x8 bq[2][2], bq2[2][2];           // fixed roles: nh0 / nh1

    auto RD_A = [&](bf16x8 (&d)[4][2], int buf, int mh) {
#pragma unroll
        for (int m = 0; m < 4; ++m) { d[m][0] = LDA(buf, mh, m, 0); d[m][1] = LDA(buf, mh, m, 1); }
    };
    auto RD_B = [&](bf16x8 (&d)[2][2], int buf, int nh) {
#pragma unroll
        for (int n = 0; n < 2; ++n) { d[n][0] = LDB(buf, nh, n, 0); d[n][1] = LDB(buf, nh, n, 1); }
    };
    auto MFMA_Q = [&](bf16x8 (&a_)[4][2], bf16x8 (&b_)[2][2], int mo, int no) {
        __builtin_amdgcn_s_setprio(1);
#pragma unroll
        for (int kk = 0; kk < 2; ++kk)
#pragma unroll
            for (int m = 0; m < 4; ++m)
#pragma unroll
                for (int n = 0; n < 2; ++n)
                    acc[mo + m][no + n] = __builtin_amdgcn_mfma_f32_16x16x32_bf16(
                        a_[m][kk], b_[n][kk], acc[mo + m][no + n], 0, 0, 0);
        __builtin_amdgcn_s_setprio(0);
    };

    const int NT = K >> 6;

    // prologue: tile0 complete; drain; then seed steady in-flight pattern
    // [Au0(1), Au1(1), Bnh1(1)] (virtual tile -1's P2/P3/P4 slots).
    STAGE_A(0, 0, 0); STAGE_A(0, 1, 0); STAGE_B(0, 0, 0); STAGE_B(0, 1, 0);
    WAITV(0);
    STAGE_A(1, 0, 1); STAGE_A(1, 1, 1); STAGE_B(1, 1, 1);
    BARRIER();                    // tile0 visible
    RD_A(af, 0, 0);               // af(0,u0)  (virtual P4(-1) preload)
    RD_B(bq, 0, 0);               // bq(0,nh0)

    for (int t = 0; t < NT; ++t) {
        const int cur = t & 1, nxt = cur ^ 1;
        // ---- P1: Q00(af,bq) ; stage Bnh0(t+1) ; read af2(cur,u1) ----
        if (t + 1 < NT) STAGE_B(nxt, 0, t + 1);
        RD_A(af2, cur, 1);
        MFMA_Q(af, bq, 0, 0);     // compiler lgkm-gates on af/bq (issued P4(t-1))
        BARRIER();
        // ---- P2: Q10(af2,bq) ; stage Au0(t+2) ; read bq2(cur,nh1) ----
        RD_B(bq2, cur, 1);
        if (t + 2 < NT) STAGE_A(cur, 0, t + 2);
        MFMA_Q(af2, bq, 4, 0);
        BARRIER();
        // ---- P3: Q01(af,bq2) ; stage Au1(t+2) ----
        if (t + 2 < NT) STAGE_A(cur, 1, t + 2);
        MFMA_Q(af, bq2, 0, 2);
        BARRIER();
        // ---- P4: Q11(af2,bq2) ; stage Bnh1(t+2) ; vis gate ; preload t+1 ----
        if (t + 2 < NT) STAGE_B(cur, 1, t + 2);
        if (t >= NT - 3) { WAITV(0); } else { WAITV(6); }
        BARRIER();                // tile t+1 visible
        if (t + 1 < NT) { RD_A(af, nxt, 0); RD_B(bq, nxt, 0); }
        MFMA_Q(af2, bq2, 4, 2);
        // no closing barrier needed: P1(t+1)'s stage writes nh0(t), consumed @P1(t)
    }

    // epilogue: D mapping col = l15, row = l4*4 + j within each 16x16 fragment
#pragma unroll
    for (int nf = 0; nf < 4; ++nf) {
        const long col = n0 + wc * 64 + nf * 16 + l15;
        const float bv = bias[col];
#pragma unroll
        for (int mf = 0; mf < 8; ++mf) {
            float* Cp = C + (m0 + wr * 128 + mf * 16 + l4 * 4) * (long)N + col;
#pragma unroll
            for (int j = 0; j < 4; ++j)
                Cp[(long)j * N] = acc[mf][nf][j] + bv;
        }
    }
}

// fallback: m97-structure 128x128 (verified round 1)
__global__ __launch_bounds__(256) void gemm_bt_bias(const unsigned short* __restrict__ A,
                                                    const unsigned short* __restrict__ B,
                                                    const float* __restrict__ bias,
                                                    float* __restrict__ C,
                                                    int M, int N, int K) {
    __shared__ unsigned short lds_a[128 * 32];
    __shared__ unsigned short lds_b[128 * 32];
    const int tid  = threadIdx.x;
    const int lane = tid & 63;
    const int wave = tid >> 6;
    const int wrr = wave >> 1, wcc = wave & 1;
    const int l15 = lane & 15, l4 = lane >> 4;
    const int nTilesN = N / 128;
    const long m0 = (long)(blockIdx.x / nTilesN) * 128;
    const long n0 = (long)(blockIdx.x % nTilesN) * 128;
    f32x4 acc[4][4] = {};
    const unsigned short* aSrc = A + (m0 + (tid >> 2)) * (long)K + ((tid & 3) * 8);
    const unsigned short* bSrc = B + (n0 + (tid >> 2)) * (long)K + ((tid & 3) * 8);
    char* aDst = (char*)lds_a + tid * 16;
    char* bDst = (char*)lds_b + tid * 16;
    for (int k0 = 0; k0 < K; k0 += 32) {
#pragma unroll
        for (int i = 0; i < 2; i++) {
            GLL(aSrc + (long)i * 64 * K + k0, aDst + i * 4096);
            GLL(bSrc + (long)i * 64 * K + k0, bDst + i * 4096);
        }
        __syncthreads();
        bf16x8 afr[4], bfr[4];
#pragma unroll
        for (int r = 0; r < 4; r++)
            afr[r] = *(const bf16x8*)&lds_a[(wrr * 64 + r * 16 + l15) * 32 + l4 * 8];
#pragma unroll
        for (int c = 0; c < 4; c++)
            bfr[c] = *(const bf16x8*)&lds_b[(wcc * 64 + c * 16 + l15) * 32 + l4 * 8];
#pragma unroll
        for (int r = 0; r < 4; r++)
#pragma unroll
            for (int c = 0; c < 4; c++)
                acc[r][c] = __builtin_amdgcn_mfma_f32_16x16x32_bf16(afr[r], bfr[c], acc[r][c], 0, 0, 0);
        __syncthreads();
    }
#pragma unroll
    for (int c = 0; c < 4; c++) {
        const long n = n0 + wcc * 64 + c * 16 + l15;
        const float bv = bias[n];
#pragma unroll
        for (int r = 0; r < 4; r++) {
            const long m = m0 + wrr * 64 + r * 16 + l4 * 4;
            float* Cp = C + m * (long)N + n;
#pragma unroll
            for (int j = 0; j < 4; j++)
                Cp[(long)j * N] = acc[r][c][j] + bv;
        }
    }
}

extern "C" void kernel_launch(void* const* d_in, const int* in_sizes, int n_in,
                              void* d_out, int out_size, void* d_ws, size_t ws_size,
                              hipStream_t stream) {
    const float* x    = (const float*)d_in[0];
    const float* w    = (const float*)d_in[1];
    const float* bias = (const float*)d_in[2];
    float* out = (float*)d_out;

    const long Nn = in_sizes[2];             // OUT = 4096
    const long Kk = (long)in_sizes[1] / Nn;  // IN  = 16384
    const long Mm = (long)in_sizes[0] / Kk;  // B*S = 8192

    unsigned short* aB = (unsigned short*)d_ws;
    unsigned short* bB = aB + Mm * Kk;
    cvt_f32_bf16<<<2048, 256, 0, stream>>>(x, aB, Mm * Kk);
    cvt_f32_bf16<<<2048, 256, 0, stream>>>(w, bB, Nn * Kk);

    if ((Mm & 255) == 0 && (Nn & 255) == 0 && (Kk & 127) == 0 && Kk >= 256) {
        const int grid = (int)((Mm >> 8) * (Nn >> 8));
        gemm256_pf<<<grid, 512, 0, stream>>>(aB, bB, bias, out, (int)Mm, (int)Nn, (int)Kk);
    } else {
        const int grid = (int)((Mm / 128) * (Nn / 128));
        gemm_bt_bias<<<grid, 256, 0, stream>>>(aB, bB, bias, out, (int)Mm, (int)Nn, (int)Kk);
    }
}